// Round 12
// baseline (230.104 us; speedup 1.0000x reference)
//
#include <hip/hip_runtime.h>
#include <hip/hip_cooperative_groups.h>

namespace cg = cooperative_groups;

#define DIM 256
#define KCAT 512
#define BM 128
#define BK 64
#define LSTR 72   // LDS row stride in u16 (64 + 8 pad)
#define CNB 80
#define CNT 1024

typedef unsigned short u16;
typedef unsigned int u32;
typedef __bf16 bf16x8 __attribute__((ext_vector_type(8)));
typedef float f32x4 __attribute__((ext_vector_type(4)));

__device__ inline float bf2f(u16 u){ union{u32 i; float f;} v; v.i=((u32)u)<<16; return v.f; }
__device__ inline u16 f2bf(float f){
  union{float f; u32 i;} v; v.f=f;
  u32 i=v.i;
  return (u16)((i + 0x7FFFu + ((i>>16)&1u)) >> 16);  // RNE
}
__device__ inline ushort4 cvt4(float4 v){
  ushort4 r; r.x=f2bf(v.x); r.y=f2bf(v.y); r.z=f2bf(v.z); r.w=f2bf(v.w); return r;
}
__device__ inline void acc2(float& a, float& b, u32 u){
  union{u32 i; float f;} lo, hi;
  lo.i = u << 16; hi.i = u & 0xffff0000u;
  a += lo.f; b += hi.f;
}
__device__ inline u32 pack2(float a, float b){
  return (u32)f2bf(a) | ((u32)f2bf(b) << 16);
}

// ===== fused CSR build (cooperative, 80 blocks x 1024 thr) =====
// zero -> hist + cvtW + cvtX -> two-level scan -> scatter
__global__ __launch_bounds__(CNT) void k_csr(
    const int* __restrict__ src, const int* __restrict__ dst, int E,
    const float* __restrict__ x, const float* __restrict__ Wl, const float* __restrict__ Wr,
    int* __restrict__ counts, int* __restrict__ offsets, int* __restrict__ cursor,
    int* __restrict__ sorted, int* __restrict__ blocksum, int* __restrict__ blockpref,
    u16* __restrict__ xb, u16* __restrict__ Wcat, int n_nodes, int nX4, int nW4)
{
  cg::grid_group grid = cg::this_grid();
  __shared__ int sm[20];
  int t = threadIdx.x, b = blockIdx.x;
  int g = b*CNT + t;
  const int G = CNB*CNT;               // 81920
  int lane = t & 63, wid = t >> 6;     // 16 waves

  // phase 0: zero counts
  for(int i=g; i<n_nodes; i+=G) counts[i] = 0;
  grid.sync();

  // phase 1: hist (atomics hidden behind the streaming converts)
  int E4 = E >> 2;
  for(int e=g; e<E4; e+=G){
    int4 d = ((const int4*)dst)[e];
    atomicAdd(counts + d.x, 1);
    atomicAdd(counts + d.y, 1);
    atomicAdd(counts + d.z, 1);
    atomicAdd(counts + d.w, 1);
  }
  if (g == 0) for(int e2 = E4*4; e2 < E; e2++) atomicAdd(counts + dst[e2], 1);
  for(int i=g; i<2*nW4; i+=G){
    int sel = (i >= nW4);
    int ii  = sel ? i - nW4 : i;
    float4 v = sel ? ((const float4*)Wr)[ii] : ((const float4*)Wl)[ii];
    int col = ii >> 6, k4 = ii & 63;
    ((ushort4*)Wcat)[col*128 + sel*64 + k4] = cvt4(v);
  }
  for(int i=g; i<nX4; i+=G) ((ushort4*)xb)[i] = cvt4(((const float4*)x)[i]);
  grid.sync();

  // phase 2: two-level exclusive scan (one count/thread; nblk = 20 blocks active)
  int nblk = (n_nodes + CNT - 1) / CNT;
  int myv = (g < n_nodes) ? counts[g] : 0;
  int sc = myv;
  #pragma unroll
  for(int off=1; off<64; off<<=1){ int v = __shfl_up(sc, off, 64); if(lane >= off) sc += v; }
  if (lane == 63) sm[wid] = sc;
  __syncthreads();
  if (t == 0){
    int run = 0;
    #pragma unroll
    for(int w=0; w<16; w++){ int v = sm[w]; sm[w] = run; run += v; }
    blocksum[b] = run;
  }
  __syncthreads();
  int myprefix = sm[wid] + (sc - myv);
  grid.sync();

  if (b == 0 && wid == 0){
    int v2 = (lane < nblk) ? blocksum[lane] : 0;
    int s2 = v2;
    #pragma unroll
    for(int off=1; off<64; off<<=1){ int u = __shfl_up(s2, off, 64); if(lane >= off) s2 += u; }
    if (lane < nblk) blockpref[lane] = s2 - v2;
    if (lane == nblk-1) offsets[n_nodes] = s2;
  }
  grid.sync();

  if (g < n_nodes){
    int off = blockpref[b] + myprefix;
    offsets[g] = off;
    cursor[g]  = off;
  }
  grid.sync();

  // phase 3: scatter into CSR order
  for(int e=g; e<E4; e+=G){
    int4 s = ((const int4*)src)[e];
    int4 d = ((const int4*)dst)[e];
    sorted[atomicAdd(cursor + d.x, 1)] = s.x;
    sorted[atomicAdd(cursor + d.y, 1)] = s.y;
    sorted[atomicAdd(cursor + d.z, 1)] = s.z;
    sorted[atomicAdd(cursor + d.w, 1)] = s.w;
  }
  if (g == 0) for(int e2 = E4*4; e2 < E; e2++)
    sorted[atomicAdd(cursor + dst[e2], 1)] = src[e2];
}

// ===== fallback CSR kernels (round-11, known good) =====
__global__ __launch_bounds__(256) void k_hist(const int* __restrict__ dst, int E,
    int* __restrict__ counts){
  int E4 = E >> 2;
  int e = blockIdx.x*256 + threadIdx.x;
  if(e < E4){
    int4 d = ((const int4*)dst)[e];
    atomicAdd(counts + d.x, 1);
    atomicAdd(counts + d.y, 1);
    atomicAdd(counts + d.z, 1);
    atomicAdd(counts + d.w, 1);
  }
  if (e == 0){
    for(int e2 = E4*4; e2 < E; e2++) atomicAdd(counts + dst[e2], 1);
  }
}

__global__ __launch_bounds__(1024) void k_scan(const int* __restrict__ counts, int n,
                                               int* __restrict__ offsets, int* __restrict__ cursor){
  __shared__ int wsum[16];
  int t = threadIdx.x;
  int s0 = t*20;
  int4 c[5];
  int s = 0;
  #pragma unroll
  for(int u=0; u<5; u++){
    int i = s0 + 4*u;
    int4 cv = {0,0,0,0};
    if (i + 3 < n){
      cv = *(const int4*)(counts + i);
    } else {
      if (i   < n) cv.x = counts[i];
      if (i+1 < n) cv.y = counts[i+1];
      if (i+2 < n) cv.z = counts[i+2];
      if (i+3 < n) cv.w = counts[i+3];
    }
    c[u] = cv;
    s += cv.x + cv.y + cv.z + cv.w;
  }
  int lane = t & 63, wid = t >> 6;
  int sc = s;
  #pragma unroll
  for(int off=1; off<64; off<<=1){
    int v = __shfl_up(sc, off, 64);
    if (lane >= off) sc += v;
  }
  if (lane == 63) wsum[wid] = sc;
  __syncthreads();
  if (t == 0){
    int run = 0;
    #pragma unroll
    for(int w=0; w<16; w++){ int v = wsum[w]; wsum[w] = run; run += v; }
  }
  __syncthreads();
  int run = wsum[wid] + (sc - s);
  #pragma unroll
  for(int u=0; u<5; u++){
    int i = s0 + 4*u;
    int4 o;
    o.x = run; run += c[u].x;
    o.y = run; run += c[u].y;
    o.z = run; run += c[u].z;
    o.w = run; run += c[u].w;
    if (i + 3 < n){
      *(int4*)(offsets + i) = o;
      *(int4*)(cursor  + i) = o;
    } else {
      if (i   < n){ offsets[i]   = o.x; cursor[i]   = o.x; }
      if (i+1 < n){ offsets[i+1] = o.y; cursor[i+1] = o.y; }
      if (i+2 < n){ offsets[i+2] = o.z; cursor[i+2] = o.z; }
      if (i+3 < n){ offsets[i+3] = o.w; cursor[i+3] = o.w; }
    }
  }
  if (t == 1023) offsets[n] = wsum[15] + sc;
}

__global__ __launch_bounds__(256) void k_scatter_cvt(const int* __restrict__ src,
    const int* __restrict__ dst, int E, int* __restrict__ cursor, int* __restrict__ sorted_src,
    const float* __restrict__ x, const float* __restrict__ Wl, const float* __restrict__ Wr,
    u16* __restrict__ xb, u16* __restrict__ Wcat, int nX4, int nW4){
  int E4 = E >> 2;
  int sb = (E4 + 255) >> 8;
  int wb = (2*nW4 + 255) >> 8;
  int b = blockIdx.x, t = threadIdx.x;
  if (b < sb){
    int e = b*256 + t;
    if(e < E4){
      int4 s = ((const int4*)src)[e];
      int4 d = ((const int4*)dst)[e];
      sorted_src[atomicAdd(cursor + d.x, 1)] = s.x;
      sorted_src[atomicAdd(cursor + d.y, 1)] = s.y;
      sorted_src[atomicAdd(cursor + d.z, 1)] = s.z;
      sorted_src[atomicAdd(cursor + d.w, 1)] = s.w;
    }
    if (b==0 && t==0){
      for(int e2 = E4*4; e2 < E; e2++)
        sorted_src[atomicAdd(cursor + dst[e2], 1)] = src[e2];
    }
  } else if (b < sb + wb){
    int i = (b - sb)*256 + t;
    if (i < 2*nW4){
      int sel = (i >= nW4);
      int ii = sel ? i - nW4 : i;
      float4 v = sel ? ((const float4*)Wr)[ii] : ((const float4*)Wl)[ii];
      int col = ii >> 6, k4 = ii & 63;
      ((ushort4*)Wcat)[col*128 + sel*64 + k4] = cvt4(v);
    }
  } else {
    int i = (b - sb - wb)*256 + t;
    if (i < nX4) ((ushort4*)xb)[i] = cvt4(((const float4*)x)[i]);
  }
}

// ===== aggregation: one wave/node; paired-edge 16B loads =====
// lanes 0-31 take even edges, 32-63 odd; lane covers 8 channels (c8).
// One load instruction now fetches TWO rows (1KB/wave). Final combine:
// 8 shfl_xor(32) per node.
__global__ __launch_bounds__(256) void k_aggr(const u16* __restrict__ xb,
    const int* __restrict__ offsets, const int* __restrict__ sorted_src,
    u16* __restrict__ aggr, int n_nodes){
  int wave = threadIdx.x >> 6, lane = threadIdx.x & 63;
  int node = blockIdx.x*4 + wave;
  if(node >= n_nodes) return;
  int b0 = offsets[node], b1 = offsets[node+1];
  int half = lane >> 5;
  int c8 = (lane & 31)*8;
  const u16* xc = xb + c8;
  float s0=0,s1=0,s2=0,s3=0,s4=0,s5=0,s6=0,s7=0;
  int i = b0 + half;
  for(; i + 6 < b1; i += 8){
    int r0 = sorted_src[i],   r1 = sorted_src[i+2];
    int r2 = sorted_src[i+4], r3 = sorted_src[i+6];
    uint4 v0 = *(const uint4*)(xc + (size_t)r0*DIM);
    uint4 v1 = *(const uint4*)(xc + (size_t)r1*DIM);
    uint4 v2 = *(const uint4*)(xc + (size_t)r2*DIM);
    uint4 v3 = *(const uint4*)(xc + (size_t)r3*DIM);
    acc2(s0,s1,v0.x); acc2(s2,s3,v0.y); acc2(s4,s5,v0.z); acc2(s6,s7,v0.w);
    acc2(s0,s1,v1.x); acc2(s2,s3,v1.y); acc2(s4,s5,v1.z); acc2(s6,s7,v1.w);
    acc2(s0,s1,v2.x); acc2(s2,s3,v2.y); acc2(s4,s5,v2.z); acc2(s6,s7,v2.w);
    acc2(s0,s1,v3.x); acc2(s2,s3,v3.y); acc2(s4,s5,v3.z); acc2(s6,s7,v3.w);
  }
  for(; i < b1; i += 2){
    int r = sorted_src[i];
    uint4 v = *(const uint4*)(xc + (size_t)r*DIM);
    acc2(s0,s1,v.x); acc2(s2,s3,v.y); acc2(s4,s5,v.z); acc2(s6,s7,v.w);
  }
  // combine halves
  s0 += __shfl_xor(s0, 32, 64); s1 += __shfl_xor(s1, 32, 64);
  s2 += __shfl_xor(s2, 32, 64); s3 += __shfl_xor(s3, 32, 64);
  s4 += __shfl_xor(s4, 32, 64); s5 += __shfl_xor(s5, 32, 64);
  s6 += __shfl_xor(s6, 32, 64); s7 += __shfl_xor(s7, 32, 64);
  int deg = b1 - b0;
  float inv = 1.0f / (float)(deg > 1 ? deg : 1);
  if (half == 0){
    uint4 o;
    o.x = pack2(s0*inv, s1*inv);
    o.y = pack2(s2*inv, s3*inv);
    o.z = pack2(s4*inv, s5*inv);
    o.w = pack2(s6*inv, s7*inv);
    *(uint4*)(aggr + (size_t)node*DIM + c8) = o;
  }
}

// ===== LDS-tiled GEMM (round-11, unchanged) =====
__global__ __launch_bounds__(256) void k_gemm(const u16* __restrict__ aggr,
    const u16* __restrict__ xb, const u16* __restrict__ Wcat, const float* __restrict__ br,
    float* __restrict__ out, int n_nodes){
  __shared__ u16 At[BM*LSTR];
  __shared__ u16 Bt[BM*LSTR];
  int t = threadIdx.x, wid = t >> 6, lane = t & 63;
  int quad = lane >> 4, l16 = lane & 15;
  int half = blockIdx.x & 1;
  int mb   = blockIdx.x >> 1;
  int row0 = mb*BM;

  f32x4 acc0[8], acc1[8];
  #pragma unroll
  for(int i=0;i<8;i++){ f32x4 z = {0.f,0.f,0.f,0.f}; acc0[i]=z; acc1[i]=z; }

  #pragma unroll 1
  for(int kc=0; kc<8; kc++){
    const u16* Asrc = (kc < 4) ? (aggr + kc*BK) : (xb + (kc-4)*BK);
    #pragma unroll
    for(int it=0; it<4; it++){
      int idx = t + it*256;
      int r = idx >> 3, c = idx & 7;
      int grow = row0 + r; if (grow >= n_nodes) grow = n_nodes - 1;
      uint4 v = *(const uint4*)(Asrc + (size_t)grow*DIM + c*8);
      *(uint4*)(&At[r*LSTR + c*8]) = v;
    }
    #pragma unroll
    for(int it=0; it<4; it++){
      int idx = t + it*256;
      int col = idx >> 3, c = idx & 7;
      uint4 v = *(const uint4*)(Wcat + (size_t)(half*128 + col)*KCAT + kc*BK + c*8);
      *(uint4*)(&Bt[col*LSTR + c*8]) = v;
    }
    __syncthreads();
    #pragma unroll
    for(int kt=0; kt<2; kt++){
      bf16x8 a0 = *(const bf16x8*)(&At[(wid*32      + l16)*LSTR + kt*32 + quad*8]);
      bf16x8 a1 = *(const bf16x8*)(&At[(wid*32 + 16 + l16)*LSTR + kt*32 + quad*8]);
      #pragma unroll
      for(int ct=0; ct<8; ct++){
        bf16x8 b = *(const bf16x8*)(&Bt[(ct*16 + l16)*LSTR + kt*32 + quad*8]);
        acc0[ct] = __builtin_amdgcn_mfma_f32_16x16x32_bf16(a0, b, acc0[ct], 0, 0, 0);
        acc1[ct] = __builtin_amdgcn_mfma_f32_16x16x32_bf16(a1, b, acc1[ct], 0, 0, 0);
      }
    }
    __syncthreads();
  }

  int colb = half*128;
  #pragma unroll
  for(int ct=0; ct<8; ct++){
    int col = colb + ct*16 + l16;
    float bi = br[col];
    int r0 = row0 + wid*32 + quad*4;
    #pragma unroll
    for(int r=0;r<4;r++){
      int rowA = r0 + r;
      if (rowA < n_nodes) out[(size_t)rowA*DIM + col] = acc0[ct][r] + bi;
      int rowB = r0 + 16 + r;
      if (rowB < n_nodes) out[(size_t)rowB*DIM + col] = acc1[ct][r] + bi;
    }
  }
}

extern "C" void kernel_launch(void* const* d_in, const int* in_sizes, int n_in,
                              void* d_out, int out_size, void* d_ws, size_t ws_size,
                              hipStream_t stream){
  const float* x  = (const float*)d_in[0];
  const int*   ei = (const int*)d_in[1];
  const float* Wl = (const float*)d_in[2];
  const float* Wr = (const float*)d_in[3];
  const float* br = (const float*)d_in[4];
  float* out = (float*)d_out;
  int n_nodes = in_sizes[0] / DIM;   // 20000
  int E = in_sizes[1] / 2;           // 320000
  const int* src = ei;
  const int* dst = ei + E;

  // workspace layout (16B aligned sections): ~12 MB
  int* counts    = (int*)d_ws;                   // [n]
  int* offsets   = counts + n_nodes;             // [n+1] (padded to n+8)
  int* cursor    = offsets + (n_nodes + 8);      // [n]
  int* blocksum  = cursor + n_nodes;             // [128]
  int* blockpref = blocksum + 128;               // [128]
  int* sorted    = blockpref + 128;              // [E]
  u16* xb        = (u16*)(sorted + E);           // [n*DIM] bf16
  u16* aggr      = xb + (size_t)n_nodes*DIM;     // [n*DIM] bf16
  u16* Wcat      = aggr + (size_t)n_nodes*DIM;   // [256*512] bf16: [Wl | Wr] per col

  int nX4 = n_nodes*DIM/4, nW4 = DIM*DIM/4;
  int E4 = E >> 2;
  int mtiles = (n_nodes + BM - 1) / BM;          // 157
  int gemm_blocks = mtiles*2;                    // 314

  void* args[] = {
    (void*)&src, (void*)&dst, (void*)&E,
    (void*)&x, (void*)&Wl, (void*)&Wr,
    (void*)&counts, (void*)&offsets, (void*)&cursor, (void*)&sorted,
    (void*)&blocksum, (void*)&blockpref,
    (void*)&xb, (void*)&Wcat, (void*)&n_nodes, (void*)&nX4, (void*)&nW4
  };
  hipError_t rc = hipLaunchCooperativeKernel((void*)k_csr, dim3(CNB), dim3(CNT),
                                             args, 0, stream);
  if (rc != hipSuccess){
    int scat_blocks = ((E4+255)>>8) + ((2*nW4+255)>>8) + ((nX4+255)>>8);
    hipMemsetAsync(counts, 0, (size_t)n_nodes*sizeof(int), stream);
    hipLaunchKernelGGL(k_hist,        dim3((E4+255)/256),  dim3(256), 0, stream,
                       dst, E, counts);
    hipLaunchKernelGGL(k_scan,        dim3(1),             dim3(1024),0, stream,
                       counts, n_nodes, offsets, cursor);
    hipLaunchKernelGGL(k_scatter_cvt, dim3(scat_blocks),   dim3(256), 0, stream,
                       src, dst, E, cursor, sorted, x, Wl, Wr, xb, Wcat, nX4, nW4);
  }
  hipLaunchKernelGGL(k_aggr,          dim3((n_nodes+3)/4), dim3(256), 0, stream,
                     xb, offsets, sorted, aggr, n_nodes);
  hipLaunchKernelGGL(k_gemm,          dim3(gemm_blocks),   dim3(256), 0, stream,
                     aggr, xb, Wcat, br, out, n_nodes);
}

// Round 13
// 167.170 us; speedup vs baseline: 1.3765x; 1.3765x over previous
//
#include <hip/hip_runtime.h>

#define DIM 256
#define KCAT 512
#define BM 128
#define BK 64
#define LSTR 72   // LDS row stride in u16 (64 + 8 pad; conflict-free fragment reads)

typedef unsigned short u16;
typedef unsigned int u32;
typedef __bf16 bf16x8 __attribute__((ext_vector_type(8)));
typedef float f32x4 __attribute__((ext_vector_type(4)));

__device__ inline float bf2f(u16 u){ union{u32 i; float f;} v; v.i=((u32)u)<<16; return v.f; }
__device__ inline u16 f2bf(float f){
  union{float f; u32 i;} v; v.f=f;
  u32 i=v.i;
  return (u16)((i + 0x7FFFu + ((i>>16)&1u)) >> 16);  // RNE
}
__device__ inline ushort4 cvt4(float4 v){
  ushort4 r; r.x=f2bf(v.x); r.y=f2bf(v.y); r.z=f2bf(v.z); r.w=f2bf(v.w); return r;
}
__device__ inline void acc2(float& a, float& b, u32 u){
  union{u32 i; float f;} lo, hi;
  lo.i = u << 16; hi.i = u & 0xffff0000u;
  a += lo.f; b += hi.f;
}
__device__ inline u32 pack2(float a, float b){
  return (u32)f2bf(a) | ((u32)f2bf(b) << 16);
}

// ---- 1: in-degree histogram (int4 edges) ----
__global__ __launch_bounds__(256) void k_hist(const int* __restrict__ dst, int E,
    int* __restrict__ counts){
  int E4 = E >> 2;
  int e = blockIdx.x*256 + threadIdx.x;
  if(e < E4){
    int4 d = ((const int4*)dst)[e];
    atomicAdd(counts + d.x, 1);
    atomicAdd(counts + d.y, 1);
    atomicAdd(counts + d.z, 1);
    atomicAdd(counts + d.w, 1);
  }
  if (e == 0){
    for(int e2 = E4*4; e2 < E; e2++) atomicAdd(counts + dst[e2], 1);
  }
}

// ---- 2: exclusive scan over counts (single block, 20/thread, static regs) ----
__global__ __launch_bounds__(1024) void k_scan(const int* __restrict__ counts, int n,
                                               int* __restrict__ offsets, int* __restrict__ cursor){
  __shared__ int wsum[16];
  int t = threadIdx.x;
  int s0 = t*20;
  int4 c[5];
  int s = 0;
  #pragma unroll
  for(int u=0; u<5; u++){
    int i = s0 + 4*u;
    int4 cv = {0,0,0,0};
    if (i + 3 < n){
      cv = *(const int4*)(counts + i);
    } else {
      if (i   < n) cv.x = counts[i];
      if (i+1 < n) cv.y = counts[i+1];
      if (i+2 < n) cv.z = counts[i+2];
      if (i+3 < n) cv.w = counts[i+3];
    }
    c[u] = cv;
    s += cv.x + cv.y + cv.z + cv.w;
  }
  int lane = t & 63, wid = t >> 6;
  int sc = s;
  #pragma unroll
  for(int off=1; off<64; off<<=1){
    int v = __shfl_up(sc, off, 64);
    if (lane >= off) sc += v;
  }
  if (lane == 63) wsum[wid] = sc;
  __syncthreads();
  if (t == 0){
    int run = 0;
    #pragma unroll
    for(int w=0; w<16; w++){ int v = wsum[w]; wsum[w] = run; run += v; }
  }
  __syncthreads();
  int run = wsum[wid] + (sc - s);
  #pragma unroll
  for(int u=0; u<5; u++){
    int i = s0 + 4*u;
    int4 o;
    o.x = run; run += c[u].x;
    o.y = run; run += c[u].y;
    o.z = run; run += c[u].z;
    o.w = run; run += c[u].w;
    if (i + 3 < n){
      *(int4*)(offsets + i) = o;
      *(int4*)(cursor  + i) = o;
    } else {
      if (i   < n){ offsets[i]   = o.x; cursor[i]   = o.x; }
      if (i+1 < n){ offsets[i+1] = o.y; cursor[i+1] = o.y; }
      if (i+2 < n){ offsets[i+2] = o.z; cursor[i+2] = o.z; }
      if (i+3 < n){ offsets[i+3] = o.w; cursor[i+3] = o.w; }
    }
  }
  if (t == 1023) offsets[n] = wsum[15] + sc;
}

// ---- 3: scatter (int4) + x->bf16 + W->bf16 (overlaps the atomic latency) ----
__global__ __launch_bounds__(256) void k_scatter_cvt(const int* __restrict__ src,
    const int* __restrict__ dst, int E, int* __restrict__ cursor, int* __restrict__ sorted_src,
    const float* __restrict__ x, const float* __restrict__ Wl, const float* __restrict__ Wr,
    u16* __restrict__ xb, u16* __restrict__ Wcat, int nX4, int nW4){
  int E4 = E >> 2;
  int sb = (E4 + 255) >> 8;
  int wb = (2*nW4 + 255) >> 8;
  int b = blockIdx.x, t = threadIdx.x;
  if (b < sb){
    int e = b*256 + t;
    if(e < E4){
      int4 s = ((const int4*)src)[e];
      int4 d = ((const int4*)dst)[e];
      sorted_src[atomicAdd(cursor + d.x, 1)] = s.x;
      sorted_src[atomicAdd(cursor + d.y, 1)] = s.y;
      sorted_src[atomicAdd(cursor + d.z, 1)] = s.z;
      sorted_src[atomicAdd(cursor + d.w, 1)] = s.w;
    }
    if (b==0 && t==0){
      for(int e2 = E4*4; e2 < E; e2++)
        sorted_src[atomicAdd(cursor + dst[e2], 1)] = src[e2];
    }
  } else if (b < sb + wb){
    int i = (b - sb)*256 + t;
    if (i < 2*nW4){
      int sel = (i >= nW4);
      int ii = sel ? i - nW4 : i;
      float4 v = sel ? ((const float4*)Wr)[ii] : ((const float4*)Wl)[ii];
      int col = ii >> 6, k4 = ii & 63;
      ((ushort4*)Wcat)[col*128 + sel*64 + k4] = cvt4(v);
    }
  } else {
    int i = (b - sb - wb)*256 + t;
    if (i < nX4) ((ushort4*)xb)[i] = cvt4(((const float4*)x)[i]);
  }
}

// ---- 4: aggregation, paired-edge 16B loads ----
// One wave/node: lanes 0-31 even edges, 32-63 odd edges; lane owns 8 channels.
// One dwordx4 fetches half of TWO rows' worth per step-pair (1KB/wave/instr vs
// 512B in the dwordx2 version). Combine halves: 8 shfl_xor(32)/node.
__global__ __launch_bounds__(256) void k_aggr(const u16* __restrict__ xb,
    const int* __restrict__ offsets, const int* __restrict__ sorted_src,
    u16* __restrict__ aggr, int n_nodes){
  int wave = threadIdx.x >> 6, lane = threadIdx.x & 63;
  int node = blockIdx.x*4 + wave;
  if(node >= n_nodes) return;
  int b0 = offsets[node], b1 = offsets[node+1];
  int half = lane >> 5;
  int c8 = (lane & 31)*8;
  const u16* xc = xb + c8;
  float s0=0,s1=0,s2=0,s3=0,s4=0,s5=0,s6=0,s7=0;
  int i = b0 + half;
  for(; i + 6 < b1; i += 8){
    int r0 = sorted_src[i],   r1 = sorted_src[i+2];
    int r2 = sorted_src[i+4], r3 = sorted_src[i+6];
    uint4 v0 = *(const uint4*)(xc + (size_t)r0*DIM);
    uint4 v1 = *(const uint4*)(xc + (size_t)r1*DIM);
    uint4 v2 = *(const uint4*)(xc + (size_t)r2*DIM);
    uint4 v3 = *(const uint4*)(xc + (size_t)r3*DIM);
    acc2(s0,s1,v0.x); acc2(s2,s3,v0.y); acc2(s4,s5,v0.z); acc2(s6,s7,v0.w);
    acc2(s0,s1,v1.x); acc2(s2,s3,v1.y); acc2(s4,s5,v1.z); acc2(s6,s7,v1.w);
    acc2(s0,s1,v2.x); acc2(s2,s3,v2.y); acc2(s4,s5,v2.z); acc2(s6,s7,v2.w);
    acc2(s0,s1,v3.x); acc2(s2,s3,v3.y); acc2(s4,s5,v3.z); acc2(s6,s7,v3.w);
  }
  for(; i < b1; i += 2){
    int r = sorted_src[i];
    uint4 v = *(const uint4*)(xc + (size_t)r*DIM);
    acc2(s0,s1,v.x); acc2(s2,s3,v.y); acc2(s4,s5,v.z); acc2(s6,s7,v.w);
  }
  s0 += __shfl_xor(s0, 32, 64); s1 += __shfl_xor(s1, 32, 64);
  s2 += __shfl_xor(s2, 32, 64); s3 += __shfl_xor(s3, 32, 64);
  s4 += __shfl_xor(s4, 32, 64); s5 += __shfl_xor(s5, 32, 64);
  s6 += __shfl_xor(s6, 32, 64); s7 += __shfl_xor(s7, 32, 64);
  int deg = b1 - b0;
  float inv = 1.0f / (float)(deg > 1 ? deg : 1);
  if (half == 0){
    uint4 o;
    o.x = pack2(s0*inv, s1*inv);
    o.y = pack2(s2*inv, s3*inv);
    o.z = pack2(s4*inv, s5*inv);
    o.w = pack2(s6*inv, s7*inv);
    *(uint4*)(aggr + (size_t)node*DIM + c8) = o;
  }
}

// ---- 5: LDS-tiled GEMM (round-11, unchanged — 168 µs config's workhorse) ----
__global__ __launch_bounds__(256) void k_gemm(const u16* __restrict__ aggr,
    const u16* __restrict__ xb, const u16* __restrict__ Wcat, const float* __restrict__ br,
    float* __restrict__ out, int n_nodes){
  __shared__ u16 At[BM*LSTR];
  __shared__ u16 Bt[BM*LSTR];
  int t = threadIdx.x, wid = t >> 6, lane = t & 63;
  int quad = lane >> 4, l16 = lane & 15;
  int half = blockIdx.x & 1;
  int mb   = blockIdx.x >> 1;
  int row0 = mb*BM;

  f32x4 acc0[8], acc1[8];
  #pragma unroll
  for(int i=0;i<8;i++){ f32x4 z = {0.f,0.f,0.f,0.f}; acc0[i]=z; acc1[i]=z; }

  #pragma unroll 1
  for(int kc=0; kc<8; kc++){
    const u16* Asrc = (kc < 4) ? (aggr + kc*BK) : (xb + (kc-4)*BK);
    #pragma unroll
    for(int it=0; it<4; it++){
      int idx = t + it*256;
      int r = idx >> 3, c = idx & 7;
      int grow = row0 + r; if (grow >= n_nodes) grow = n_nodes - 1;
      uint4 v = *(const uint4*)(Asrc + (size_t)grow*DIM + c*8);
      *(uint4*)(&At[r*LSTR + c*8]) = v;
    }
    #pragma unroll
    for(int it=0; it<4; it++){
      int idx = t + it*256;
      int col = idx >> 3, c = idx & 7;
      uint4 v = *(const uint4*)(Wcat + (size_t)(half*128 + col)*KCAT + kc*BK + c*8);
      *(uint4*)(&Bt[col*LSTR + c*8]) = v;
    }
    __syncthreads();
    #pragma unroll
    for(int kt=0; kt<2; kt++){
      bf16x8 a0 = *(const bf16x8*)(&At[(wid*32      + l16)*LSTR + kt*32 + quad*8]);
      bf16x8 a1 = *(const bf16x8*)(&At[(wid*32 + 16 + l16)*LSTR + kt*32 + quad*8]);
      #pragma unroll
      for(int ct=0; ct<8; ct++){
        bf16x8 b = *(const bf16x8*)(&Bt[(ct*16 + l16)*LSTR + kt*32 + quad*8]);
        acc0[ct] = __builtin_amdgcn_mfma_f32_16x16x32_bf16(a0, b, acc0[ct], 0, 0, 0);
        acc1[ct] = __builtin_amdgcn_mfma_f32_16x16x32_bf16(a1, b, acc1[ct], 0, 0, 0);
      }
    }
    __syncthreads();
  }

  int colb = half*128;
  #pragma unroll
  for(int ct=0; ct<8; ct++){
    int col = colb + ct*16 + l16;
    float bi = br[col];
    int r0 = row0 + wid*32 + quad*4;
    #pragma unroll
    for(int r=0;r<4;r++){
      int rowA = r0 + r;
      if (rowA < n_nodes) out[(size_t)rowA*DIM + col] = acc0[ct][r] + bi;
      int rowB = r0 + 16 + r;
      if (rowB < n_nodes) out[(size_t)rowB*DIM + col] = acc1[ct][r] + bi;
    }
  }
}

extern "C" void kernel_launch(void* const* d_in, const int* in_sizes, int n_in,
                              void* d_out, int out_size, void* d_ws, size_t ws_size,
                              hipStream_t stream){
  const float* x  = (const float*)d_in[0];
  const int*   ei = (const int*)d_in[1];
  const float* Wl = (const float*)d_in[2];
  const float* Wr = (const float*)d_in[3];
  const float* br = (const float*)d_in[4];
  float* out = (float*)d_out;
  int n_nodes = in_sizes[0] / DIM;   // 20000
  int E = in_sizes[1] / 2;           // 320000
  const int* src = ei;
  const int* dst = ei + E;

  // workspace layout (16B aligned sections): ~12 MB
  int* counts  = (int*)d_ws;                   // [n]
  int* offsets = counts + n_nodes;             // [n+1] (padded to n+8)
  int* cursor  = offsets + (n_nodes + 8);      // [n]
  int* sorted  = cursor + n_nodes;             // [E]
  u16* xb      = (u16*)(sorted + E);           // [n*DIM] bf16
  u16* aggr    = xb + (size_t)n_nodes*DIM;     // [n*DIM] bf16
  u16* Wcat    = aggr + (size_t)n_nodes*DIM;   // [256*512] bf16: [Wl | Wr] per col

  int nX4 = n_nodes*DIM/4, nW4 = DIM*DIM/4;
  int E4 = E >> 2;
  int scat_blocks = ((E4+255)>>8) + ((2*nW4+255)>>8) + ((nX4+255)>>8);
  int mtiles = (n_nodes + BM - 1) / BM;        // 157
  int gemm_blocks = mtiles*2;                  // 314

  hipMemsetAsync(counts, 0, (size_t)n_nodes*sizeof(int), stream);
  hipLaunchKernelGGL(k_hist,        dim3((E4+255)/256),  dim3(256), 0, stream,
                     dst, E, counts);
  hipLaunchKernelGGL(k_scan,        dim3(1),             dim3(1024),0, stream,
                     counts, n_nodes, offsets, cursor);
  hipLaunchKernelGGL(k_scatter_cvt, dim3(scat_blocks),   dim3(256), 0, stream,
                     src, dst, E, cursor, sorted, x, Wl, Wr, xb, Wcat, nX4, nW4);
  hipLaunchKernelGGL(k_aggr,        dim3((n_nodes+3)/4), dim3(256), 0, stream,
                     xb, offsets, sorted, aggr, n_nodes);
  hipLaunchKernelGGL(k_gemm,        dim3(gemm_blocks),   dim3(256), 0, stream,
                     aggr, xb, Wcat, br, out, n_nodes);
}

// Round 14
// 166.303 us; speedup vs baseline: 1.3836x; 1.0052x over previous
//
#include <hip/hip_runtime.h>

#define DIM 256
#define KCAT 512
#define BM 128
#define BN 64
#define BK 64
#define LSTR 72   // LDS row stride in u16 (64 + 8 pad; 2-way max bank aliasing = free)

typedef unsigned short u16;
typedef unsigned int u32;
typedef __bf16 bf16x8 __attribute__((ext_vector_type(8)));
typedef float f32x4 __attribute__((ext_vector_type(4)));

__device__ inline float bf2f(u16 u){ union{u32 i; float f;} v; v.i=((u32)u)<<16; return v.f; }
__device__ inline u16 f2bf(float f){
  union{float f; u32 i;} v; v.f=f;
  u32 i=v.i;
  return (u16)((i + 0x7FFFu + ((i>>16)&1u)) >> 16);  // RNE
}
__device__ inline ushort4 cvt4(float4 v){
  ushort4 r; r.x=f2bf(v.x); r.y=f2bf(v.y); r.z=f2bf(v.z); r.w=f2bf(v.w); return r;
}
__device__ inline void acc2(float& a, float& b, u32 u){
  union{u32 i; float f;} lo, hi;
  lo.i = u << 16; hi.i = u & 0xffff0000u;
  a += lo.f; b += hi.f;
}
__device__ inline u32 pack2(float a, float b){
  return (u32)f2bf(a) | ((u32)f2bf(b) << 16);
}

// ---- 1: in-degree histogram (int4 edges) ----
__global__ __launch_bounds__(256) void k_hist(const int* __restrict__ dst, int E,
    int* __restrict__ counts){
  int E4 = E >> 2;
  int e = blockIdx.x*256 + threadIdx.x;
  if(e < E4){
    int4 d = ((const int4*)dst)[e];
    atomicAdd(counts + d.x, 1);
    atomicAdd(counts + d.y, 1);
    atomicAdd(counts + d.z, 1);
    atomicAdd(counts + d.w, 1);
  }
  if (e == 0){
    for(int e2 = E4*4; e2 < E; e2++) atomicAdd(counts + dst[e2], 1);
  }
}

// ---- 2: exclusive scan over counts (single block, 20/thread, static regs) ----
__global__ __launch_bounds__(1024) void k_scan(const int* __restrict__ counts, int n,
                                               int* __restrict__ offsets, int* __restrict__ cursor){
  __shared__ int wsum[16];
  int t = threadIdx.x;
  int s0 = t*20;
  int4 c[5];
  int s = 0;
  #pragma unroll
  for(int u=0; u<5; u++){
    int i = s0 + 4*u;
    int4 cv = {0,0,0,0};
    if (i + 3 < n){
      cv = *(const int4*)(counts + i);
    } else {
      if (i   < n) cv.x = counts[i];
      if (i+1 < n) cv.y = counts[i+1];
      if (i+2 < n) cv.z = counts[i+2];
      if (i+3 < n) cv.w = counts[i+3];
    }
    c[u] = cv;
    s += cv.x + cv.y + cv.z + cv.w;
  }
  int lane = t & 63, wid = t >> 6;
  int sc = s;
  #pragma unroll
  for(int off=1; off<64; off<<=1){
    int v = __shfl_up(sc, off, 64);
    if (lane >= off) sc += v;
  }
  if (lane == 63) wsum[wid] = sc;
  __syncthreads();
  if (t == 0){
    int run = 0;
    #pragma unroll
    for(int w=0; w<16; w++){ int v = wsum[w]; wsum[w] = run; run += v; }
  }
  __syncthreads();
  int run = wsum[wid] + (sc - s);
  #pragma unroll
  for(int u=0; u<5; u++){
    int i = s0 + 4*u;
    int4 o;
    o.x = run; run += c[u].x;
    o.y = run; run += c[u].y;
    o.z = run; run += c[u].z;
    o.w = run; run += c[u].w;
    if (i + 3 < n){
      *(int4*)(offsets + i) = o;
      *(int4*)(cursor  + i) = o;
    } else {
      if (i   < n){ offsets[i]   = o.x; cursor[i]   = o.x; }
      if (i+1 < n){ offsets[i+1] = o.y; cursor[i+1] = o.y; }
      if (i+2 < n){ offsets[i+2] = o.z; cursor[i+2] = o.z; }
      if (i+3 < n){ offsets[i+3] = o.w; cursor[i+3] = o.w; }
    }
  }
  if (t == 1023) offsets[n] = wsum[15] + sc;
}

// ---- 3: scatter (int4) + x->bf16 + W->bf16 (overlaps the atomic latency) ----
__global__ __launch_bounds__(256) void k_scatter_cvt(const int* __restrict__ src,
    const int* __restrict__ dst, int E, int* __restrict__ cursor, int* __restrict__ sorted_src,
    const float* __restrict__ x, const float* __restrict__ Wl, const float* __restrict__ Wr,
    u16* __restrict__ xb, u16* __restrict__ Wcat, int nX4, int nW4){
  int E4 = E >> 2;
  int sb = (E4 + 255) >> 8;
  int wb = (2*nW4 + 255) >> 8;
  int b = blockIdx.x, t = threadIdx.x;
  if (b < sb){
    int e = b*256 + t;
    if(e < E4){
      int4 s = ((const int4*)src)[e];
      int4 d = ((const int4*)dst)[e];
      sorted_src[atomicAdd(cursor + d.x, 1)] = s.x;
      sorted_src[atomicAdd(cursor + d.y, 1)] = s.y;
      sorted_src[atomicAdd(cursor + d.z, 1)] = s.z;
      sorted_src[atomicAdd(cursor + d.w, 1)] = s.w;
    }
    if (b==0 && t==0){
      for(int e2 = E4*4; e2 < E; e2++)
        sorted_src[atomicAdd(cursor + dst[e2], 1)] = src[e2];
    }
  } else if (b < sb + wb){
    int i = (b - sb)*256 + t;
    if (i < 2*nW4){
      int sel = (i >= nW4);
      int ii = sel ? i - nW4 : i;
      float4 v = sel ? ((const float4*)Wr)[ii] : ((const float4*)Wl)[ii];
      int col = ii >> 6, k4 = ii & 63;
      ((ushort4*)Wcat)[col*128 + sel*64 + k4] = cvt4(v);
    }
  } else {
    int i = (b - sb - wb)*256 + t;
    if (i < nX4) ((ushort4*)xb)[i] = cvt4(((const float4*)x)[i]);
  }
}

// ---- 4: aggregation, paired-edge 16B loads (round-13, neutral-kept) ----
__global__ __launch_bounds__(256) void k_aggr(const u16* __restrict__ xb,
    const int* __restrict__ offsets, const int* __restrict__ sorted_src,
    u16* __restrict__ aggr, int n_nodes){
  int wave = threadIdx.x >> 6, lane = threadIdx.x & 63;
  int node = blockIdx.x*4 + wave;
  if(node >= n_nodes) return;
  int b0 = offsets[node], b1 = offsets[node+1];
  int half = lane >> 5;
  int c8 = (lane & 31)*8;
  const u16* xc = xb + c8;
  float s0=0,s1=0,s2=0,s3=0,s4=0,s5=0,s6=0,s7=0;
  int i = b0 + half;
  for(; i + 6 < b1; i += 8){
    int r0 = sorted_src[i],   r1 = sorted_src[i+2];
    int r2 = sorted_src[i+4], r3 = sorted_src[i+6];
    uint4 v0 = *(const uint4*)(xc + (size_t)r0*DIM);
    uint4 v1 = *(const uint4*)(xc + (size_t)r1*DIM);
    uint4 v2 = *(const uint4*)(xc + (size_t)r2*DIM);
    uint4 v3 = *(const uint4*)(xc + (size_t)r3*DIM);
    acc2(s0,s1,v0.x); acc2(s2,s3,v0.y); acc2(s4,s5,v0.z); acc2(s6,s7,v0.w);
    acc2(s0,s1,v1.x); acc2(s2,s3,v1.y); acc2(s4,s5,v1.z); acc2(s6,s7,v1.w);
    acc2(s0,s1,v2.x); acc2(s2,s3,v2.y); acc2(s4,s5,v2.z); acc2(s6,s7,v2.w);
    acc2(s0,s1,v3.x); acc2(s2,s3,v3.y); acc2(s4,s5,v3.z); acc2(s6,s7,v3.w);
  }
  for(; i < b1; i += 2){
    int r = sorted_src[i];
    uint4 v = *(const uint4*)(xc + (size_t)r*DIM);
    acc2(s0,s1,v.x); acc2(s2,s3,v.y); acc2(s4,s5,v.z); acc2(s6,s7,v.w);
  }
  s0 += __shfl_xor(s0, 32, 64); s1 += __shfl_xor(s1, 32, 64);
  s2 += __shfl_xor(s2, 32, 64); s3 += __shfl_xor(s3, 32, 64);
  s4 += __shfl_xor(s4, 32, 64); s5 += __shfl_xor(s5, 32, 64);
  s6 += __shfl_xor(s6, 32, 64); s7 += __shfl_xor(s7, 32, 64);
  int deg = b1 - b0;
  float inv = 1.0f / (float)(deg > 1 ? deg : 1);
  if (half == 0){
    uint4 o;
    o.x = pack2(s0*inv, s1*inv);
    o.y = pack2(s2*inv, s3*inv);
    o.z = pack2(s4*inv, s5*inv);
    o.w = pack2(s6*inv, s7*inv);
    *(uint4*)(aggr + (size_t)node*DIM + c8) = o;
  }
}

// ---- 5: LDS-tiled GEMM, BM=128 x BN=64 -> 628 blocks (~2.5/CU co-resident) ----
// Same proven layout as round 11, but half the N-tile: when one block stalls
// on its staging barrier, a sibling block on the same CU computes (m114-style
// implicit overlap that 314 blocks couldn't provide).
// Wave w: rows [w*32,w*32+32) x 64 cols. Per kc: 4 A-stage + 2 B-stage iters,
// then 2 kt x (2 A reads + 4 B reads + 8 MFMAs). acc = 8 f32x4 = 32 VGPRs.
__global__ __launch_bounds__(256) void k_gemm(const u16* __restrict__ aggr,
    const u16* __restrict__ xb, const u16* __restrict__ Wcat, const float* __restrict__ br,
    float* __restrict__ out, int n_nodes){
  __shared__ u16 At[BM*LSTR];   // 18432 B
  __shared__ u16 Bt[BN*LSTR];   //  9216 B
  int t = threadIdx.x, wid = t >> 6, lane = t & 63;
  int quad = lane >> 4, l16 = lane & 15;
  int q  = blockIdx.x & 3;           // col quarter: cols [q*64, q*64+64)
  int mb = blockIdx.x >> 2;
  int row0 = mb*BM;

  f32x4 acc0[4], acc1[4];
  #pragma unroll
  for(int i=0;i<4;i++){ f32x4 z = {0.f,0.f,0.f,0.f}; acc0[i]=z; acc1[i]=z; }

  #pragma unroll 1
  for(int kc=0; kc<8; kc++){
    const u16* Asrc = (kc < 4) ? (aggr + kc*BK) : (xb + (kc-4)*BK);
    // stage A chunk: 128 rows x 64 u16 (8 x 16B per row), 4 iters
    #pragma unroll
    for(int it=0; it<4; it++){
      int idx = t + it*256;
      int r = idx >> 3, c = idx & 7;
      int grow = row0 + r; if (grow >= n_nodes) grow = n_nodes - 1;
      uint4 v = *(const uint4*)(Asrc + (size_t)grow*DIM + c*8);
      *(uint4*)(&At[r*LSTR + c*8]) = v;
    }
    // stage B chunk: 64 cols x 64 u16, 2 iters
    #pragma unroll
    for(int it=0; it<2; it++){
      int idx = t + it*256;
      int col = idx >> 3, c = idx & 7;
      uint4 v = *(const uint4*)(Wcat + (size_t)(q*BN + col)*KCAT + kc*BK + c*8);
      *(uint4*)(&Bt[col*LSTR + c*8]) = v;
    }
    __syncthreads();
    #pragma unroll
    for(int kt=0; kt<2; kt++){
      bf16x8 a0 = *(const bf16x8*)(&At[(wid*32      + l16)*LSTR + kt*32 + quad*8]);
      bf16x8 a1 = *(const bf16x8*)(&At[(wid*32 + 16 + l16)*LSTR + kt*32 + quad*8]);
      #pragma unroll
      for(int ct=0; ct<4; ct++){
        bf16x8 b = *(const bf16x8*)(&Bt[(ct*16 + l16)*LSTR + kt*32 + quad*8]);
        acc0[ct] = __builtin_amdgcn_mfma_f32_16x16x32_bf16(a0, b, acc0[ct], 0, 0, 0);
        acc1[ct] = __builtin_amdgcn_mfma_f32_16x16x32_bf16(a1, b, acc1[ct], 0, 0, 0);
      }
    }
    __syncthreads();
  }

  // epilogue
  int colb = q*BN;
  #pragma unroll
  for(int ct=0; ct<4; ct++){
    int col = colb + ct*16 + l16;
    float bi = br[col];
    int r0 = row0 + wid*32 + quad*4;
    #pragma unroll
    for(int r=0;r<4;r++){
      int rowA = r0 + r;
      if (rowA < n_nodes) out[(size_t)rowA*DIM + col] = acc0[ct][r] + bi;
      int rowB = r0 + 16 + r;
      if (rowB < n_nodes) out[(size_t)rowB*DIM + col] = acc1[ct][r] + bi;
    }
  }
}

extern "C" void kernel_launch(void* const* d_in, const int* in_sizes, int n_in,
                              void* d_out, int out_size, void* d_ws, size_t ws_size,
                              hipStream_t stream){
  const float* x  = (const float*)d_in[0];
  const int*   ei = (const int*)d_in[1];
  const float* Wl = (const float*)d_in[2];
  const float* Wr = (const float*)d_in[3];
  const float* br = (const float*)d_in[4];
  float* out = (float*)d_out;
  int n_nodes = in_sizes[0] / DIM;   // 20000
  int E = in_sizes[1] / 2;           // 320000
  const int* src = ei;
  const int* dst = ei + E;

  // workspace layout (16B aligned sections): ~12 MB
  int* counts  = (int*)d_ws;                   // [n]
  int* offsets = counts + n_nodes;             // [n+1] (padded to n+8)
  int* cursor  = offsets + (n_nodes + 8);      // [n]
  int* sorted  = cursor + n_nodes;             // [E]
  u16* xb      = (u16*)(sorted + E);           // [n*DIM] bf16
  u16* aggr    = xb + (size_t)n_nodes*DIM;     // [n*DIM] bf16
  u16* Wcat    = aggr + (size_t)n_nodes*DIM;   // [256*512] bf16: [Wl | Wr] per col

  int nX4 = n_nodes*DIM/4, nW4 = DIM*DIM/4;
  int E4 = E >> 2;
  int scat_blocks = ((E4+255)>>8) + ((2*nW4+255)>>8) + ((nX4+255)>>8);
  int mtiles = (n_nodes + BM - 1) / BM;        // 157
  int gemm_blocks = mtiles*4;                  // 628

  hipMemsetAsync(counts, 0, (size_t)n_nodes*sizeof(int), stream);
  hipLaunchKernelGGL(k_hist,        dim3((E4+255)/256),  dim3(256), 0, stream,
                     dst, E, counts);
  hipLaunchKernelGGL(k_scan,        dim3(1),             dim3(1024),0, stream,
                     counts, n_nodes, offsets, cursor);
  hipLaunchKernelGGL(k_scatter_cvt, dim3(scat_blocks),   dim3(256), 0, stream,
                     src, dst, E, cursor, sorted, x, Wl, Wr, xb, Wcat, nX4, nW4);
  hipLaunchKernelGGL(k_aggr,        dim3((n_nodes+3)/4), dim3(256), 0, stream,
                     xb, offsets, sorted, aggr, n_nodes);
  hipLaunchKernelGGL(k_gemm,        dim3(gemm_blocks),   dim3(256), 0, stream,
                     aggr, xb, Wcat, br, out, n_nodes);
}